// Round 1
// baseline (43720.328 us; speedup 1.0000x reference)
//
#include <hip/hip_runtime.h>
#include <cstdint>
#include <cstddef>

// ---------------------------------------------------------------------------
// Tacotron decoder, MI355X. Round 0: correctness-first fp32.
// Structure: each batch row b is an independent 250-step recurrent chain
// (weight_per is output-only -> atomicAdd). One block per b, states in LDS,
// no grid syncs. 4 graph nodes total.
// ---------------------------------------------------------------------------

#define TDEC   250
#define BATCH  128
#define TENC   1024
#define DENC   256

#define SEQ_OFF    ((size_t)0)
#define ALPHA_OFF  ((size_t)12800000)        // 128*1250*80
#define ALPHA_SZ   ((size_t)32768000)        // 250*128*1024
#define WP_OFF     ((size_t)45568000)        // + above

__device__ inline float ftanh(float x){
    float e = __expf(2.f*x);                      // inf-safe: x>>0 -> 1, x<<0 -> -1
    return 1.f - 2.f*__builtin_amdgcn_rcpf(e + 1.f);
}
__device__ inline float fsig(float x){
    return __builtin_amdgcn_rcpf(1.f + __expf(-x));
}

// ---------------- block-wide reductions (blockDim.x == 1024) ----------------
__device__ inline float block_reduce_sum(float v, float* red, int tid){
    #pragma unroll
    for (int off = 32; off; off >>= 1) v += __shfl_xor(v, off, 64);
    __syncthreads();                       // protect red[] from previous use
    if ((tid & 63) == 0) red[tid >> 6] = v;
    __syncthreads();
    if (tid == 0){
        float s = red[0];
        #pragma unroll
        for (int i = 1; i < 16; i++) s += red[i];
        red[16] = s;
    }
    __syncthreads();
    return red[16];
}
__device__ inline float block_reduce_max(float v, float* red, int tid){
    #pragma unroll
    for (int off = 32; off; off >>= 1) v = fmaxf(v, __shfl_xor(v, off, 64));
    __syncthreads();
    if ((tid & 63) == 0) red[tid >> 6] = v;
    __syncthreads();
    if (tid == 0){
        float s = red[0];
        #pragma unroll
        for (int i = 1; i < 16; i++) s = fmaxf(s, red[i]);
        red[16] = s;
    }
    __syncthreads();
    return red[16];
}

// ---------------- GEMV: y[j] = act(dot(x, W[:,j]) + b[j]), 1024 threads -----
// W row-major [K, STRIDE]; N outputs; N2=2^LG thread tiles; K split over
// 1024/N2 parts, partials combined through LDS scratch.
// ACT: 0 none, 1 sigmoid, 2 tanh, 3 relu
template<int ACT, int K, int N, int LG, int STRIDE>
__device__ inline void gemv(const float* __restrict__ W, const float* __restrict__ bias,
                            const float* __restrict__ x, float* __restrict__ y,
                            float* scratch, int tid)
{
    constexpr int N2   = 1 << LG;
    constexpr int PCNT = 1024 >> LG;
    constexpr int KCNT = K / PCNT;
    static_assert(KCNT * PCNT == K, "K must divide");
    const int j    = tid & (N2 - 1);
    const int part = tid >> LG;
    float acc = 0.f;
    if (N == N2 || j < N){
        const float* Wp = W + (size_t)(part * KCNT) * STRIDE + j;
        const float* xp = x + part * KCNT;
        #pragma unroll 8
        for (int k = 0; k < KCNT; k++) acc += xp[k] * Wp[(size_t)k * STRIDE];
    }
    scratch[tid] = acc;
    __syncthreads();
    if (tid < N){
        float s = bias[tid];
        #pragma unroll
        for (int p2 = 0; p2 < PCNT; p2++) s += scratch[tid + (p2 << LG)];
        if      (ACT == 1) s = fsig(s);
        else if (ACT == 2) s = ftanh(s);
        else if (ACT == 3) s = fmaxf(s, 0.f);
        y[tid] = s;
    }
    __syncthreads();
}

// ---------------- K1: keys = enc @ Wk + bk  ([131072,256] x [256,256]) ------
// 64 rows/block, k-tiles of 64 in LDS, acc[16] float4 per thread.
__global__ __launch_bounds__(256) void k_keys(const float* __restrict__ enc,
                                              const float* __restrict__ Wk,
                                              const float* __restrict__ bk,
                                              float* __restrict__ keys)
{
    __shared__ __align__(16) float Wt[64 * 256];   // [kk][d]
    __shared__ float At[64 * 64];                  // [r][kk]
    const int tid = threadIdx.x;
    const size_t row0 = (size_t)blockIdx.x * 64;
    const int dq = tid & 63;          // float4 column group: d = dq*4
    const int rg = tid >> 6;          // row group (16 rows each)

    float4 acc[16];
    #pragma unroll
    for (int i = 0; i < 16; i++) acc[i] = float4{0.f, 0.f, 0.f, 0.f};

    for (int k0 = 0; k0 < 256; k0 += 64){
        __syncthreads();
        #pragma unroll
        for (int i = 0; i < 64; i++)
            Wt[i * 256 + tid] = Wk[(size_t)(k0 + i) * 256 + tid];
        #pragma unroll
        for (int i = 0; i < 16; i++){
            int idx = tid + i * 256;
            int r = idx >> 6, kk = idx & 63;
            At[idx] = enc[(row0 + r) * 256 + k0 + kk];
        }
        __syncthreads();
        for (int kk = 0; kk < 64; kk++){
            float4 w = ((const float4*)Wt)[kk * 64 + dq];
            #pragma unroll
            for (int rr = 0; rr < 16; rr++){
                float a = At[(rg * 16 + rr) * 64 + kk];
                acc[rr].x += a * w.x; acc[rr].y += a * w.y;
                acc[rr].z += a * w.z; acc[rr].w += a * w.w;
            }
        }
    }
    float4 bb = ((const float4*)bk)[dq];
    #pragma unroll
    for (int rr = 0; rr < 16; rr++){
        size_t row = row0 + rg * 16 + rr;
        float4 o{acc[rr].x + bb.x, acc[rr].y + bb.y, acc[rr].z + bb.z, acc[rr].w + bb.w};
        ((float4*)keys)[row * 64 + dq] = o;
    }
}

// ---------------- K2: main recurrent kernel, block = batch row b ------------
struct KParams {
    const float *enc; const int *imask; const float *inp_att; const float *style_tok;
    const float *pre_W1, *pre_b1, *pre_W2, *pre_b2;
    const float *att_Wg, *att_bg, *att_Wc, *att_bc;
    const float *attn_Wq, *attn_bq, *attn_v;
    const float *deci_W, *deci_b;
    const float *dec1_Wg, *dec1_bg, *dec1_Wc, *dec1_bc;
    const float *dec2_Wg, *dec2_bg, *dec2_Wc, *dec2_bc;
    const float *out_W, *out_b;
    const float *keys; float *wacc; float *out;
};

__global__ __launch_bounds__(1024, 1) void k_main(KParams p)
{
    __shared__ float h_att[256], h1[256], h2[256], ctxl[256], wctxl[256];
    __shared__ float stylel[256], astylel[256];
    __shared__ __align__(16) float q_l[256];
    __shared__ __align__(16) float v_l[256];
    __shared__ float p1_l[256], p_l[128], c_l[256], dec_in[256], o1_l[256], o2_l[256];
    __shared__ float g_l[512], xa[640], xd[512], dense_l[400], last_o[80];
    __shared__ float e_l[1024], scratch[1024];
    __shared__ float red[32];

    const int tid = threadIdx.x;
    const int b   = blockIdx.x;
    const int mlen = p.imask[b];          // 1..1024

    // ---- init per-b state ----
    if (tid < 256){
        h_att[tid] = 0.f; h1[tid] = 0.f; h2[tid] = 0.f; ctxl[tid] = 0.f;
        float s = 0.f;
        #pragma unroll
        for (int k = 0; k < 10; k++) s += p.inp_att[b * 10 + k] * p.style_tok[k * 256 + tid];
        stylel[tid] = s; astylel[tid] = fabsf(s);
        v_l[tid] = p.attn_v[tid];
    }
    if (tid < 80) last_o[tid] = 0.f;
    __syncthreads();

    for (int s = 0; s < TDEC; s++){
        // ---- prenet ----
        gemv<3,  80, 256, 8, 256>(p.pre_W1, p.pre_b1, last_o, p1_l, scratch, tid);
        gemv<3, 256, 128, 7, 128>(p.pre_W2, p.pre_b2, p1_l,  p_l,  scratch, tid);

        // ---- attention GRU:  x = [ctx, p], h = h_att ----
        if (tid < 640) xa[tid] = (tid < 256) ? ctxl[tid]
                               : (tid < 384) ? p_l[tid - 256]
                               : h_att[tid - 384];
        __syncthreads();
        gemv<1, 640, 512, 9, 512>(p.att_Wg, p.att_bg, xa, g_l, scratch, tid);   // [r,u]
        if (tid < 256) xa[384 + tid] = g_l[tid] * h_att[tid];                    // r*h
        __syncthreads();
        gemv<2, 640, 256, 8, 256>(p.att_Wc, p.att_bc, xa, c_l, scratch, tid);   // c
        if (tid < 256){
            float u = g_l[256 + tid];
            h_att[tid] = u * h_att[tid] + (1.f - u) * c_l[tid];
        }
        __syncthreads();
        gemv<0, 256, 256, 8, 256>(p.attn_Wq, p.attn_bq, h_att, q_l, scratch, tid); // q

        // ---- attention energies + softmax ----
        float ev = -1e30f;
        if (tid < mlen){
            const float4* kr = (const float4*)(p.keys + (((size_t)b << 10) + tid) * 256);
            const float4* q4 = (const float4*)q_l;
            const float4* v4 = (const float4*)v_l;
            float sa = 0.f;
            #pragma unroll 4
            for (int i = 0; i < 64; i++){
                float4 kk = kr[i]; float4 qq = q4[i]; float4 vv = v4[i];
                sa += ftanh(kk.x + qq.x) * vv.x + ftanh(kk.y + qq.y) * vv.y
                    + ftanh(kk.z + qq.z) * vv.z + ftanh(kk.w + qq.w) * vv.w;
            }
            ev = sa;
        }
        float m  = block_reduce_max(ev, red, tid);
        float a  = (tid < mlen) ? __expf(ev - m) : 0.f;
        float sm = block_reduce_sum(a, red, tid);
        float alpha = a * __builtin_amdgcn_rcpf(sm);
        e_l[tid] = alpha;
        if (tid < mlen)
            p.out[ALPHA_OFF + (size_t)s * 131072 + ((size_t)b << 10) + tid] = alpha;
        __syncthreads();

        // ---- context ----
        {
            int d = tid & 255, pt = tid >> 8;
            float sa = 0.f;
            const float* er = p.enc + (((size_t)b << 10) << 8) + d;
            for (int t = pt; t < mlen; t += 4) sa += e_l[t] * er[(size_t)t << 8];
            scratch[tid] = sa;
        }
        __syncthreads();
        float wpv = 0.f;
        if (tid < 256){
            float cs = scratch[tid] + scratch[tid + 256] + scratch[tid + 512] + scratch[tid + 768];
            ctxl[tid]  = cs;
            wctxl[tid] = cs + stylel[tid];
            wpv = astylel[tid] * __builtin_amdgcn_rcpf(fabsf(cs) + astylel[tid]);
        }
        float wsum = block_reduce_sum(wpv, red, tid);   // internal syncs order ctx/wctx too
        if (tid == 0) atomicAdd(&p.wacc[s], wsum);

        // ---- dec_in = [h_att, wctx] @ deci_W + b ----
        if (tid < 512) xd[tid] = (tid < 256) ? h_att[tid] : wctxl[tid - 256];
        __syncthreads();
        gemv<0, 512, 256, 8, 256>(p.deci_W, p.deci_b, xd, dec_in, scratch, tid);

        // ---- GRU 1 ----
        if (tid < 512) xd[tid] = (tid < 256) ? dec_in[tid] : h1[tid - 256];
        __syncthreads();
        gemv<1, 512, 512, 9, 512>(p.dec1_Wg, p.dec1_bg, xd, g_l, scratch, tid);
        if (tid < 256) xd[256 + tid] = g_l[tid] * h1[tid];
        __syncthreads();
        gemv<2, 512, 256, 8, 256>(p.dec1_Wc, p.dec1_bc, xd, c_l, scratch, tid);
        if (tid < 256){
            float u = g_l[256 + tid];
            float hn = u * h1[tid] + (1.f - u) * c_l[tid];
            h1[tid] = hn; o1_l[tid] = hn + dec_in[tid];
        }
        __syncthreads();

        // ---- GRU 2 ----
        if (tid < 512) xd[tid] = (tid < 256) ? o1_l[tid] : h2[tid - 256];
        __syncthreads();
        gemv<1, 512, 512, 9, 512>(p.dec2_Wg, p.dec2_bg, xd, g_l, scratch, tid);
        if (tid < 256) xd[256 + tid] = g_l[tid] * h2[tid];
        __syncthreads();
        gemv<2, 512, 256, 8, 256>(p.dec2_Wc, p.dec2_bc, xd, c_l, scratch, tid);
        if (tid < 256){
            float u = g_l[256 + tid];
            float hn = u * h2[tid] + (1.f - u) * c_l[tid];
            h2[tid] = hn; o2_l[tid] = hn + o1_l[tid];
        }
        __syncthreads();

        // ---- output dense (256 -> 400), write seq2seq slice, update last_out
        gemv<0, 256, 400, 9, 400>(p.out_W, p.out_b, o2_l, dense_l, scratch, tid);
        if (tid < 400){
            float val = dense_l[tid];
            p.out[(size_t)b * 100000 + (size_t)s * 400 + tid] = val;
            if (tid >= 320) last_o[tid - 320] = val;
        }
        __syncthreads();
    }
}

// ---------------- K3: finalize weight_pers ----------------------------------
__global__ void k_final(const float* __restrict__ wacc, float* __restrict__ out)
{
    int i = threadIdx.x;
    if (i < TDEC) out[WP_OFF + i] = wacc[i] * (1.0f / 32768.0f);
}

// ---------------------------------------------------------------------------
extern "C" void kernel_launch(void* const* d_in, const int* in_sizes, int n_in,
                              void* d_out, int out_size, void* d_ws, size_t ws_size,
                              hipStream_t stream)
{
    const float* enc        = (const float*)d_in[0];
    const int*   imask      = (const int*)  d_in[1];
    const float* inp_att    = (const float*)d_in[2];
    const float* style_tok  = (const float*)d_in[3];
    const float* pre_W1     = (const float*)d_in[4];
    const float* pre_b1     = (const float*)d_in[5];
    const float* pre_W2     = (const float*)d_in[6];
    const float* pre_b2     = (const float*)d_in[7];
    const float* att_Wg     = (const float*)d_in[8];
    const float* att_bg     = (const float*)d_in[9];
    const float* att_Wc     = (const float*)d_in[10];
    const float* att_bc     = (const float*)d_in[11];
    const float* attn_Wk    = (const float*)d_in[12];
    const float* attn_bk    = (const float*)d_in[13];
    const float* attn_Wq    = (const float*)d_in[14];
    const float* attn_bq    = (const float*)d_in[15];
    const float* attn_v     = (const float*)d_in[16];
    const float* deci_W     = (const float*)d_in[17];
    const float* deci_b     = (const float*)d_in[18];
    const float* dec1_Wg    = (const float*)d_in[19];
    const float* dec1_bg    = (const float*)d_in[20];
    const float* dec1_Wc    = (const float*)d_in[21];
    const float* dec1_bc    = (const float*)d_in[22];
    const float* dec2_Wg    = (const float*)d_in[23];
    const float* dec2_bg    = (const float*)d_in[24];
    const float* dec2_Wc    = (const float*)d_in[25];
    const float* dec2_bc    = (const float*)d_in[26];
    const float* out_W      = (const float*)d_in[27];
    const float* out_b      = (const float*)d_in[28];
    // d_in[29] = decode_time_steps (250, compile-time constant here)

    float* wacc = (float*)d_ws;                 // 250 accumulators
    float* keys = (float*)d_ws + 256;           // [131072, 256] fp32 (128 MB)
    float* out  = (float*)d_out;

    // zero weight_per accumulators + alphas region (masked alphas are exactly 0)
    hipMemsetAsync(d_ws, 0, 1024, stream);
    hipMemsetAsync((char*)d_out + ALPHA_OFF * 4, 0, ALPHA_SZ * 4, stream);

    k_keys<<<2048, 256, 0, stream>>>(enc, attn_Wk, attn_bk, keys);

    KParams kp{enc, imask, inp_att, style_tok,
               pre_W1, pre_b1, pre_W2, pre_b2,
               att_Wg, att_bg, att_Wc, att_bc,
               attn_Wq, attn_bq, attn_v,
               deci_W, deci_b,
               dec1_Wg, dec1_bg, dec1_Wc, dec1_bc,
               dec2_Wg, dec2_bg, dec2_Wc, dec2_bc,
               out_W, out_b,
               keys, wacc, out};
    k_main<<<BATCH, 1024, 0, stream>>>(kp);

    k_final<<<1, 256, 0, stream>>>(wacc, out);
}

// Round 2
// 35756.320 us; speedup vs baseline: 1.2227x; 1.2227x over previous
//
#include <hip/hip_runtime.h>
#include <cstdint>
#include <cstddef>

// ---------------------------------------------------------------------------
// Tacotron decoder, MI355X. Round 1: bf16 weight/key/enc streaming + ILP GEMV.
// One block per batch row b (128 blocks), entire 250-step chain in-block.
// Weights converted to bf16 once (prep kernels), GEMV reads uint4=8xbf16 with
// 8 parallel accumulators. Keys stored transposed [b][d][t] bf16 for
// lane-coalesced energy loop. enc staged as bf16 for the context reduction.
// ---------------------------------------------------------------------------

#define TDEC   250
#define BATCH  128

#define ALPHA_OFF  ((size_t)12800000)        // 128*1250*80 floats
#define ALPHA_SZ   ((size_t)32768000)        // 250*128*1024 floats
#define WP_OFF     ((size_t)45568000)

// ---- ws byte offsets ----
#define WS_WACC_B   ((size_t)0)
#define WS_WGT_B    ((size_t)4096)
#define WGT_ELEMS   1658880
#define WS_KEYS_B   (WS_WGT_B + (size_t)WGT_ELEMS * 2)            // 3,321,856
#define WS_ENC_B    (WS_KEYS_B + (size_t)33554432 * 2)            // +64 MB
// total = 137,539,584 B = 131.2 MB (< proven-available 134.2 MB)

// ---- weight offsets (bf16 elems) ----
#define OFF_PRE_W1   0          // 80x256
#define OFF_PRE_W2   20480      // 256x128
#define OFF_ATT_WG   53248      // 640x512
#define OFF_ATT_WC   380928     // 640x256
#define OFF_ATTN_WQ  544768     // 256x256
#define OFF_DECI_W   610304     // 512x256
#define OFF_DEC1_WG  741376     // 512x512
#define OFF_DEC1_WC  1003520    // 512x256
#define OFF_DEC2_WG  1134592    // 512x512
#define OFF_DEC2_WC  1396736    // 512x256
#define OFF_OUT_WP   1527808    // 256x512 (padded from 256x400)

__device__ inline float bf2f(unsigned short u){
    return __uint_as_float(((unsigned int)u) << 16);
}
__device__ inline unsigned short f2bf(float f){
    unsigned int u = __float_as_uint(f);
    u = (u + 0x7fffu + ((u >> 16) & 1u)) >> 16;
    return (unsigned short)u;
}
__device__ inline float ftanh(float x){
    float e = __expf(2.f * x);
    return 1.f - 2.f * __builtin_amdgcn_rcpf(e + 1.f);
}
__device__ inline float fsig(float x){
    return __builtin_amdgcn_rcpf(1.f + __expf(-x));
}

// ---------------- block-wide reductions (blockDim.x == 1024) ----------------
__device__ inline float block_reduce_sum(float v, float* red, int tid){
    #pragma unroll
    for (int off = 32; off; off >>= 1) v += __shfl_xor(v, off, 64);
    __syncthreads();
    if ((tid & 63) == 0) red[tid >> 6] = v;
    __syncthreads();
    if (tid == 0){
        float s = red[0];
        #pragma unroll
        for (int i = 1; i < 16; i++) s += red[i];
        red[16] = s;
    }
    __syncthreads();
    return red[16];
}
__device__ inline float block_reduce_max(float v, float* red, int tid){
    #pragma unroll
    for (int off = 32; off; off >>= 1) v = fmaxf(v, __shfl_xor(v, off, 64));
    __syncthreads();
    if ((tid & 63) == 0) red[tid >> 6] = v;
    __syncthreads();
    if (tid == 0){
        float s = red[0];
        #pragma unroll
        for (int i = 1; i < 16; i++) s = fmaxf(s, red[i]);
        red[16] = s;
    }
    __syncthreads();
    return red[16];
}

// ---------------- bf16 GEMV: y[0:NOUT] = act(x[0:K] @ W[K][N] + b) ----------
// W bf16 row-major [K][N], N in {128,256,512}. CH = N/8 chunk-threads cover N
// with uint4 (8 bf16) loads; PARTS K-partitions; partials through scratch.
// ACT: 0 none, 1 sigmoid, 2 tanh, 3 relu
template<int ACT, int K, int N, int NOUT, int PARTS>
__device__ inline void gemv_bf(const unsigned short* __restrict__ W,
                               const float* __restrict__ bias,
                               const float* __restrict__ x, float* __restrict__ y,
                               float* scratch, int tid)
{
    constexpr int CH   = N / 8;
    constexpr int LG   = (CH == 16) ? 4 : (CH == 32) ? 5 : 6;
    constexpr int KCNT = K / PARTS;
    static_assert(KCNT * PARTS == K, "K must divide");
    static_assert(CH * PARTS <= 1024, "too many threads");
    const int chunk = tid & (CH - 1);
    const int part  = tid >> LG;
    if (PARTS == (1024 >> LG) || part < PARTS){
        const uint4* Wp = (const uint4*)W + (size_t)(part * KCNT) * (N / 8) + chunk;
        const float* xp = x + part * KCNT;
        float a0=0.f,a1=0.f,a2=0.f,a3=0.f,a4=0.f,a5=0.f,a6=0.f,a7=0.f;
        #pragma unroll 8
        for (int k = 0; k < KCNT; k++){
            uint4 w = Wp[(size_t)k * (N / 8)];
            float xv = xp[k];
            a0 = fmaf(__uint_as_float(w.x << 16),         xv, a0);
            a1 = fmaf(__uint_as_float(w.x & 0xffff0000u), xv, a1);
            a2 = fmaf(__uint_as_float(w.y << 16),         xv, a2);
            a3 = fmaf(__uint_as_float(w.y & 0xffff0000u), xv, a3);
            a4 = fmaf(__uint_as_float(w.z << 16),         xv, a4);
            a5 = fmaf(__uint_as_float(w.z & 0xffff0000u), xv, a5);
            a6 = fmaf(__uint_as_float(w.w << 16),         xv, a6);
            a7 = fmaf(__uint_as_float(w.w & 0xffff0000u), xv, a7);
        }
        float4* s4 = (float4*)(scratch + part * N + chunk * 8);
        s4[0] = float4{a0, a1, a2, a3};
        s4[1] = float4{a4, a5, a6, a7};
    }
    __syncthreads();
    if (tid < NOUT){
        float s = bias[tid];
        #pragma unroll
        for (int p = 0; p < PARTS; p++) s += scratch[p * N + tid];
        if      (ACT == 1) s = fsig(s);
        else if (ACT == 2) s = ftanh(s);
        else if (ACT == 3) s = fmaxf(s, 0.f);
        y[tid] = s;
    }
    __syncthreads();
}

// ---------------- prep: fp32 -> bf16 conversions ----------------------------
__global__ void k_cvt_flat(const float* __restrict__ src, unsigned short* __restrict__ dst, int n){
    int i = blockIdx.x * 256 + threadIdx.x;
    if (i < n) dst[i] = f2bf(src[i]);
}
// out_W [256][400] -> [256][512] zero-padded
__global__ void k_cvt_pad(const float* __restrict__ src, unsigned short* __restrict__ dst){
    int i = blockIdx.x * 256 + threadIdx.x;   // i < 256*512
    int k = i >> 9, n = i & 511;
    dst[i] = (n < 400) ? f2bf(src[k * 400 + n]) : (unsigned short)0;
}

// ---------------- K1: keys_T[b][d][t] = bf16(enc @ Wk + bk) -----------------
// 64 rows/block (within one b), fp32 math, LDS transpose, coalesced bf16 store.
__global__ __launch_bounds__(256) void k_keys(const float* __restrict__ enc,
                                              const float* __restrict__ Wk,
                                              const float* __restrict__ bk,
                                              unsigned short* __restrict__ keysT)
{
    __shared__ __align__(16) float Wt[64 * 256];   // [kk][d]
    __shared__ float At[64 * 64];                  // [r][kk]
    __shared__ unsigned short tileT[256 * 68];     // [d][t_loc], pad 68
    const int tid = threadIdx.x;
    const size_t row0 = (size_t)blockIdx.x * 64;
    const int dq = tid & 63;          // d = dq*4 + c
    const int rg = tid >> 6;          // row group (16 rows each)

    float4 acc[16];
    #pragma unroll
    for (int i = 0; i < 16; i++) acc[i] = float4{0.f, 0.f, 0.f, 0.f};

    for (int k0 = 0; k0 < 256; k0 += 64){
        __syncthreads();
        #pragma unroll
        for (int i = 0; i < 64; i++)
            Wt[i * 256 + tid] = Wk[(size_t)(k0 + i) * 256 + tid];
        #pragma unroll
        for (int i = 0; i < 16; i++){
            int idx = tid + i * 256;
            int r = idx >> 6, kk = idx & 63;
            At[idx] = enc[(row0 + r) * 256 + k0 + kk];
        }
        __syncthreads();
        for (int kk = 0; kk < 64; kk++){
            float4 w = ((const float4*)Wt)[kk * 64 + dq];
            #pragma unroll
            for (int rr = 0; rr < 16; rr++){
                float a = At[(rg * 16 + rr) * 64 + kk];
                acc[rr].x += a * w.x; acc[rr].y += a * w.y;
                acc[rr].z += a * w.z; acc[rr].w += a * w.w;
            }
        }
    }
    float4 bb = ((const float4*)bk)[dq];
    __syncthreads();
    #pragma unroll
    for (int rr = 0; rr < 16; rr++){
        int t_loc = rg * 16 + rr;
        #pragma unroll
        for (int c = 0; c < 4; c++){
            float val = (&acc[rr].x)[c] + (&bb.x)[c];
            int d = dq * 4 + c;
            tileT[d * 68 + t_loc] = f2bf(val);
        }
    }
    __syncthreads();
    const int b_ = (int)(row0 >> 10);
    const int t0 = (int)(row0 & 1023);
    #pragma unroll
    for (int i = 0; i < 16; i++){
        int flat = tid + i * 256;          // 4096 ushort4 chunks
        int d = flat >> 4, tq = flat & 15;
        ushort4 v = *(const ushort4*)&tileT[d * 68 + tq * 4];
        *(ushort4*)&keysT[(((size_t)(b_ * 256 + d)) << 10) + t0 + tq * 4] = v;
    }
}

// ---------------- K2: main recurrent kernel, block = batch row b ------------
struct KParams {
    const int *imask; const float *inp_att; const float *style_tok;
    const float *pre_b1, *pre_b2, *att_bg, *att_bc, *attn_bq, *attn_v;
    const float *deci_b, *dec1_bg, *dec1_bc, *dec2_bg, *dec2_bc, *out_b;
    const unsigned short *wgt;      // bf16 weight block
    const unsigned short *keysT;    // [128][256][1024] bf16
    const unsigned short *encb;     // [128][1024][256] bf16
    float *wacc; float *out;
};

__global__ __launch_bounds__(1024, 1) void k_main(KParams p)
{
    __shared__ float h_att[256], h1[256], h2[256], ctxl[256], wctxl[256];
    __shared__ float stylel[256], astylel[256];
    __shared__ float q_l[256], v_l[256];
    __shared__ float p1_l[256], p_l[128], c_l[256], dec_in[256], o1_l[256], o2_l[256];
    __shared__ float g_l[512], xa[640], xd[512], dense_l[400], last_o[80];
    __shared__ float e_l[1024];
    __shared__ __align__(16) float scratch[8192];   // GEMV partials (32 KB)
    __shared__ float red[32];

    const int tid = threadIdx.x;
    const int b   = blockIdx.x;
    const int mlen = p.imask[b];          // 1..1024

    const unsigned short* W = p.wgt;

    if (tid < 256){
        h_att[tid] = 0.f; h1[tid] = 0.f; h2[tid] = 0.f; ctxl[tid] = 0.f;
        float s = 0.f;
        #pragma unroll
        for (int k = 0; k < 10; k++) s += p.inp_att[b * 10 + k] * p.style_tok[k * 256 + tid];
        stylel[tid] = s; astylel[tid] = fabsf(s);
        v_l[tid] = p.attn_v[tid];
    }
    if (tid < 80) last_o[tid] = 0.f;
    __syncthreads();

    for (int s = 0; s < TDEC; s++){
        // ---- prenet ----
        gemv_bf<3,  80, 256, 256, 16>(W + OFF_PRE_W1, p.pre_b1, last_o, p1_l, scratch, tid);
        gemv_bf<3, 256, 128, 128, 64>(W + OFF_PRE_W2, p.pre_b2, p1_l,  p_l,  scratch, tid);

        // ---- attention GRU: x = [ctx, p], h = h_att ----
        if (tid < 640) xa[tid] = (tid < 256) ? ctxl[tid]
                               : (tid < 384) ? p_l[tid - 256]
                               : h_att[tid - 384];
        __syncthreads();
        gemv_bf<1, 640, 512, 512, 16>(W + OFF_ATT_WG, p.att_bg, xa, g_l, scratch, tid);
        if (tid < 256) xa[384 + tid] = g_l[tid] * h_att[tid];            // r*h
        __syncthreads();
        gemv_bf<2, 640, 256, 256, 32>(W + OFF_ATT_WC, p.att_bc, xa, c_l, scratch, tid);
        if (tid < 256){
            float u = g_l[256 + tid];
            h_att[tid] = u * h_att[tid] + (1.f - u) * c_l[tid];
        }
        __syncthreads();
        gemv_bf<0, 256, 256, 256, 32>(W + OFF_ATTN_WQ, p.attn_bq, h_att, q_l, scratch, tid);

        // ---- attention energies (keys_T coalesced) + softmax ----
        float ev = -1e30f;
        if (tid < mlen){
            const unsigned short* kp = p.keysT + (((size_t)b) << 18) + tid;
            float sa = 0.f;
            #pragma unroll 8
            for (int d = 0; d < 256; d++){
                float kk  = bf2f(kp[(size_t)d << 10]);
                sa = fmaf(ftanh(kk + q_l[d]), v_l[d], sa);
            }
            ev = sa;
        }
        float m  = block_reduce_max(ev, red, tid);
        float a  = (tid < mlen) ? __expf(ev - m) : 0.f;
        float sm = block_reduce_sum(a, red, tid);
        float alpha = a * __builtin_amdgcn_rcpf(sm);
        e_l[tid] = alpha;
        if (tid < mlen)
            p.out[ALPHA_OFF + (size_t)s * 131072 + ((size_t)b << 10) + tid] = alpha;
        __syncthreads();

        // ---- context (enc bf16) ----
        {
            int d = tid & 255, pt = tid >> 8;
            const unsigned short* er = p.encb + (((size_t)b << 10) << 8) + d;
            float sa = 0.f;
            for (int t = pt; t < mlen; t += 4)
                sa = fmaf(e_l[t], bf2f(er[(size_t)t << 8]), sa);
            scratch[tid] = sa;
        }
        __syncthreads();
        float wpv = 0.f;
        if (tid < 256){
            float cs = scratch[tid] + scratch[tid + 256] + scratch[tid + 512] + scratch[tid + 768];
            ctxl[tid]  = cs;
            wctxl[tid] = cs + stylel[tid];
            wpv = astylel[tid] * __builtin_amdgcn_rcpf(fabsf(cs) + astylel[tid]);
        }
        float wsum = block_reduce_sum(wpv, red, tid);
        if (tid == 0) atomicAdd(&p.wacc[s], wsum);

        // ---- dec_in = [h_att, wctx] @ deci_W + b ----
        if (tid < 512) xd[tid] = (tid < 256) ? h_att[tid] : wctxl[tid - 256];
        __syncthreads();
        gemv_bf<0, 512, 256, 256, 32>(W + OFF_DECI_W, p.deci_b, xd, dec_in, scratch, tid);

        // ---- GRU 1 ----
        if (tid < 512) xd[tid] = (tid < 256) ? dec_in[tid] : h1[tid - 256];
        __syncthreads();
        gemv_bf<1, 512, 512, 512, 16>(W + OFF_DEC1_WG, p.dec1_bg, xd, g_l, scratch, tid);
        if (tid < 256) xd[256 + tid] = g_l[tid] * h1[tid];
        __syncthreads();
        gemv_bf<2, 512, 256, 256, 32>(W + OFF_DEC1_WC, p.dec1_bc, xd, c_l, scratch, tid);
        if (tid < 256){
            float u = g_l[256 + tid];
            float hn = u * h1[tid] + (1.f - u) * c_l[tid];
            h1[tid] = hn; o1_l[tid] = hn + dec_in[tid];
        }
        __syncthreads();

        // ---- GRU 2 ----
        if (tid < 512) xd[tid] = (tid < 256) ? o1_l[tid] : h2[tid - 256];
        __syncthreads();
        gemv_bf<1, 512, 512, 512, 16>(W + OFF_DEC2_WG, p.dec2_bg, xd, g_l, scratch, tid);
        if (tid < 256) xd[256 + tid] = g_l[tid] * h2[tid];
        __syncthreads();
        gemv_bf<2, 512, 256, 256, 32>(W + OFF_DEC2_WC, p.dec2_bc, xd, c_l, scratch, tid);
        if (tid < 256){
            float u = g_l[256 + tid];
            float hn = u * h2[tid] + (1.f - u) * c_l[tid];
            h2[tid] = hn; o2_l[tid] = hn + o1_l[tid];
        }
        __syncthreads();

        // ---- output dense (256 -> 400 via padded 512) ----
        gemv_bf<0, 256, 512, 400, 16>(W + OFF_OUT_WP, p.out_b, o2_l, dense_l, scratch, tid);
        if (tid < 400){
            float val = dense_l[tid];
            p.out[(size_t)b * 100000 + (size_t)s * 400 + tid] = val;
            if (tid >= 320) last_o[tid - 320] = val;
        }
        __syncthreads();
    }
}

// ---------------- K3: finalize weight_pers ----------------------------------
__global__ void k_final(const float* __restrict__ wacc, float* __restrict__ out)
{
    int i = threadIdx.x;
    if (i < TDEC) out[WP_OFF + i] = wacc[i] * (1.0f / 32768.0f);
}

// ---------------------------------------------------------------------------
extern "C" void kernel_launch(void* const* d_in, const int* in_sizes, int n_in,
                              void* d_out, int out_size, void* d_ws, size_t ws_size,
                              hipStream_t stream)
{
    const float* enc        = (const float*)d_in[0];
    const int*   imask      = (const int*)  d_in[1];
    const float* inp_att    = (const float*)d_in[2];
    const float* style_tok  = (const float*)d_in[3];
    const float* pre_W1     = (const float*)d_in[4];
    const float* pre_b1     = (const float*)d_in[5];
    const float* pre_W2     = (const float*)d_in[6];
    const float* pre_b2     = (const float*)d_in[7];
    const float* att_Wg     = (const float*)d_in[8];
    const float* att_bg     = (const float*)d_in[9];
    const float* att_Wc     = (const float*)d_in[10];
    const float* att_bc     = (const float*)d_in[11];
    const float* attn_Wk    = (const float*)d_in[12];
    const float* attn_bk    = (const float*)d_in[13];
    const float* attn_Wq    = (const float*)d_in[14];
    const float* attn_bq    = (const float*)d_in[15];
    const float* attn_v     = (const float*)d_in[16];
    const float* deci_W     = (const float*)d_in[17];
    const float* deci_b     = (const float*)d_in[18];
    const float* dec1_Wg    = (const float*)d_in[19];
    const float* dec1_bg    = (const float*)d_in[20];
    const float* dec1_Wc    = (const float*)d_in[21];
    const float* dec1_bc    = (const float*)d_in[22];
    const float* dec2_Wg    = (const float*)d_in[23];
    const float* dec2_bg    = (const float*)d_in[24];
    const float* dec2_Wc    = (const float*)d_in[25];
    const float* dec2_bc    = (const float*)d_in[26];
    const float* out_W      = (const float*)d_in[27];
    const float* out_b      = (const float*)d_in[28];

    float*          wacc  = (float*)((char*)d_ws + WS_WACC_B);
    unsigned short* wgt   = (unsigned short*)((char*)d_ws + WS_WGT_B);
    unsigned short* keysT = (unsigned short*)((char*)d_ws + WS_KEYS_B);
    unsigned short* encb  = (unsigned short*)((char*)d_ws + WS_ENC_B);
    float* out = (float*)d_out;

    hipMemsetAsync(d_ws, 0, 1024, stream);
    hipMemsetAsync((char*)d_out + ALPHA_OFF * 4, 0, ALPHA_SZ * 4, stream);

    // ---- weight conversions (bf16) ----
    auto cvt = [&](const float* src, size_t off, int n){
        k_cvt_flat<<<(n + 255) / 256, 256, 0, stream>>>(src, wgt + off, n);
    };
    cvt(pre_W1,  OFF_PRE_W1,   80 * 256);
    cvt(pre_W2,  OFF_PRE_W2,  256 * 128);
    cvt(att_Wg,  OFF_ATT_WG,  640 * 512);
    cvt(att_Wc,  OFF_ATT_WC,  640 * 256);
    cvt(attn_Wq, OFF_ATTN_WQ, 256 * 256);
    cvt(deci_W,  OFF_DECI_W,  512 * 256);
    cvt(dec1_Wg, OFF_DEC1_WG, 512 * 512);
    cvt(dec1_Wc, OFF_DEC1_WC, 512 * 256);
    cvt(dec2_Wg, OFF_DEC2_WG, 512 * 512);
    cvt(dec2_Wc, OFF_DEC2_WC, 512 * 256);
    k_cvt_pad<<<(256 * 512) / 256, 256, 0, stream>>>(out_W, wgt + OFF_OUT_WP);

    // ---- enc -> bf16 ----
    k_cvt_flat<<<(33554432 + 255) / 256, 256, 0, stream>>>(enc, encb, 33554432);

    // ---- keys (transposed bf16) ----
    k_keys<<<2048, 256, 0, stream>>>(enc, attn_Wk, attn_bk, keysT);

    KParams kp{imask, inp_att, style_tok,
               pre_b1, pre_b2, att_bg, att_bc, attn_bq, attn_v,
               deci_b, dec1_bg, dec1_bc, dec2_bg, dec2_bc, out_b,
               wgt, keysT, encb, wacc, out};
    k_main<<<BATCH, 1024, 0, stream>>>(kp);

    k_final<<<1, 256, 0, stream>>>(wacc, out);
}

// Round 3
// 24447.475 us; speedup vs baseline: 1.7883x; 1.4626x over previous
//
#include <hip/hip_runtime.h>
#include <cstdint>
#include <cstddef>

// ---------------------------------------------------------------------------
// Tacotron decoder, MI355X. Round 2: attention phase rebuilt.
//  - energy/context read keysT/encb with 16B (8xbf16) coalesced loads, 32
//    independent loads per thread in flight, LDS cross-part reduction.
//  - all global outputs use nontemporal stores so the 181 MB write stream
//    stops evicting keysT/encb from the 256 MB L3 (R1 counter evidence:
//    FETCH_SIZE 57.6 MB/step == keysT+encb refetched from HBM every step).
//  - alpha memset removed; masked lanes store 0.0 themselves.
// One block per batch row b (128 blocks), whole 250-step chain in-block.
// ---------------------------------------------------------------------------

#define TDEC   250
#define BATCH  128

#define ALPHA_OFF  ((size_t)12800000)        // 128*1250*80 floats
#define WP_OFF     ((size_t)45568000)

// ---- ws byte offsets ----
#define WS_WACC_B   ((size_t)0)
#define WS_WGT_B    ((size_t)4096)
#define WGT_ELEMS   1658880
#define WS_KEYS_B   (WS_WGT_B + (size_t)WGT_ELEMS * 2)
#define WS_ENC_B    (WS_KEYS_B + (size_t)33554432 * 2)

// ---- weight offsets (bf16 elems) ----
#define OFF_PRE_W1   0          // 80x256
#define OFF_PRE_W2   20480      // 256x128
#define OFF_ATT_WG   53248      // 640x512
#define OFF_ATT_WC   380928     // 640x256
#define OFF_ATTN_WQ  544768     // 256x256
#define OFF_DECI_W   610304     // 512x256
#define OFF_DEC1_WG  741376     // 512x512
#define OFF_DEC1_WC  1003520    // 512x256
#define OFF_DEC2_WG  1134592    // 512x512
#define OFF_DEC2_WC  1396736    // 512x256
#define OFF_OUT_WP   1527808    // 256x512 (padded from 256x400)

__device__ inline float bf2f(unsigned short u){
    return __uint_as_float(((unsigned int)u) << 16);
}
__device__ inline unsigned short f2bf(float f){
    unsigned int u = __float_as_uint(f);
    u = (u + 0x7fffu + ((u >> 16) & 1u)) >> 16;
    return (unsigned short)u;
}
__device__ inline float ftanh(float x){
    float e = __expf(2.f * x);
    return 1.f - 2.f * __builtin_amdgcn_rcpf(e + 1.f);
}
__device__ inline float fsig(float x){
    return __builtin_amdgcn_rcpf(1.f + __expf(-x));
}

// ---------------- block-wide reductions (blockDim.x == 1024) ----------------
__device__ inline float block_reduce_sum(float v, float* red, int tid){
    #pragma unroll
    for (int off = 32; off; off >>= 1) v += __shfl_xor(v, off, 64);
    __syncthreads();
    if ((tid & 63) == 0) red[tid >> 6] = v;
    __syncthreads();
    if (tid == 0){
        float s = red[0];
        #pragma unroll
        for (int i = 1; i < 16; i++) s += red[i];
        red[16] = s;
    }
    __syncthreads();
    return red[16];
}
__device__ inline float block_reduce_max(float v, float* red, int tid){
    #pragma unroll
    for (int off = 32; off; off >>= 1) v = fmaxf(v, __shfl_xor(v, off, 64));
    __syncthreads();
    if ((tid & 63) == 0) red[tid >> 6] = v;
    __syncthreads();
    if (tid == 0){
        float s = red[0];
        #pragma unroll
        for (int i = 1; i < 16; i++) s = fmaxf(s, red[i]);
        red[16] = s;
    }
    __syncthreads();
    return red[16];
}

// ---------------- bf16 GEMV: y[0:NOUT] = act(x[0:K] @ W[K][N] + b) ----------
template<int ACT, int K, int N, int NOUT, int PARTS>
__device__ inline void gemv_bf(const unsigned short* __restrict__ W,
                               const float* __restrict__ bias,
                               const float* __restrict__ x, float* __restrict__ y,
                               float* scratch, int tid)
{
    constexpr int CH   = N / 8;
    constexpr int LG   = (CH == 16) ? 4 : (CH == 32) ? 5 : 6;
    constexpr int KCNT = K / PARTS;
    static_assert(KCNT * PARTS == K, "K must divide");
    static_assert(CH * PARTS <= 1024, "too many threads");
    const int chunk = tid & (CH - 1);
    const int part  = tid >> LG;
    if (PARTS == (1024 >> LG) || part < PARTS){
        const uint4* Wp = (const uint4*)W + (size_t)(part * KCNT) * (N / 8) + chunk;
        const float* xp = x + part * KCNT;
        float a0=0.f,a1=0.f,a2=0.f,a3=0.f,a4=0.f,a5=0.f,a6=0.f,a7=0.f;
        #pragma unroll 8
        for (int k = 0; k < KCNT; k++){
            uint4 w = Wp[(size_t)k * (N / 8)];
            float xv = xp[k];
            a0 = fmaf(__uint_as_float(w.x << 16),         xv, a0);
            a1 = fmaf(__uint_as_float(w.x & 0xffff0000u), xv, a1);
            a2 = fmaf(__uint_as_float(w.y << 16),         xv, a2);
            a3 = fmaf(__uint_as_float(w.y & 0xffff0000u), xv, a3);
            a4 = fmaf(__uint_as_float(w.z << 16),         xv, a4);
            a5 = fmaf(__uint_as_float(w.z & 0xffff0000u), xv, a5);
            a6 = fmaf(__uint_as_float(w.w << 16),         xv, a6);
            a7 = fmaf(__uint_as_float(w.w & 0xffff0000u), xv, a7);
        }
        float4* s4 = (float4*)(scratch + part * N + chunk * 8);
        s4[0] = float4{a0, a1, a2, a3};
        s4[1] = float4{a4, a5, a6, a7};
    }
    __syncthreads();
    if (tid < NOUT){
        float s = bias[tid];
        #pragma unroll
        for (int p = 0; p < PARTS; p++) s += scratch[p * N + tid];
        if      (ACT == 1) s = fsig(s);
        else if (ACT == 2) s = ftanh(s);
        else if (ACT == 3) s = fmaxf(s, 0.f);
        y[tid] = s;
    }
    __syncthreads();
}

// ---------------- prep: fp32 -> bf16 conversions ----------------------------
__global__ void k_cvt_flat(const float* __restrict__ src, unsigned short* __restrict__ dst, int n){
    int i = blockIdx.x * 256 + threadIdx.x;
    if (i < n) dst[i] = f2bf(src[i]);
}
__global__ void k_cvt_pad(const float* __restrict__ src, unsigned short* __restrict__ dst){
    int i = blockIdx.x * 256 + threadIdx.x;   // i < 256*512
    int k = i >> 9, n = i & 511;
    dst[i] = (n < 400) ? f2bf(src[k * 400 + n]) : (unsigned short)0;
}

// ---------------- K1: keys_T[b][d][t] = bf16(enc @ Wk + bk) -----------------
__global__ __launch_bounds__(256) void k_keys(const float* __restrict__ enc,
                                              const float* __restrict__ Wk,
                                              const float* __restrict__ bk,
                                              unsigned short* __restrict__ keysT)
{
    __shared__ __align__(16) float Wt[64 * 256];   // [kk][d]
    __shared__ float At[64 * 64];                  // [r][kk]
    __shared__ unsigned short tileT[256 * 68];     // [d][t_loc], pad 68
    const int tid = threadIdx.x;
    const size_t row0 = (size_t)blockIdx.x * 64;
    const int dq = tid & 63;
    const int rg = tid >> 6;

    float4 acc[16];
    #pragma unroll
    for (int i = 0; i < 16; i++) acc[i] = float4{0.f, 0.f, 0.f, 0.f};

    for (int k0 = 0; k0 < 256; k0 += 64){
        __syncthreads();
        #pragma unroll
        for (int i = 0; i < 64; i++)
            Wt[i * 256 + tid] = Wk[(size_t)(k0 + i) * 256 + tid];
        #pragma unroll
        for (int i = 0; i < 16; i++){
            int idx = tid + i * 256;
            int r = idx >> 6, kk = idx & 63;
            At[idx] = enc[(row0 + r) * 256 + k0 + kk];
        }
        __syncthreads();
        for (int kk = 0; kk < 64; kk++){
            float4 w = ((const float4*)Wt)[kk * 64 + dq];
            #pragma unroll
            for (int rr = 0; rr < 16; rr++){
                float a = At[(rg * 16 + rr) * 64 + kk];
                acc[rr].x += a * w.x; acc[rr].y += a * w.y;
                acc[rr].z += a * w.z; acc[rr].w += a * w.w;
            }
        }
    }
    float4 bb = ((const float4*)bk)[dq];
    __syncthreads();
    #pragma unroll
    for (int rr = 0; rr < 16; rr++){
        int t_loc = rg * 16 + rr;
        #pragma unroll
        for (int c = 0; c < 4; c++){
            float val = (&acc[rr].x)[c] + (&bb.x)[c];
            int d = dq * 4 + c;
            tileT[d * 68 + t_loc] = f2bf(val);
        }
    }
    __syncthreads();
    const int b_ = (int)(row0 >> 10);
    const int t0 = (int)(row0 & 1023);
    #pragma unroll
    for (int i = 0; i < 16; i++){
        int flat = tid + i * 256;
        int d = flat >> 4, tq = flat & 15;
        ushort4 v = *(const ushort4*)&tileT[d * 68 + tq * 4];
        *(ushort4*)&keysT[(((size_t)(b_ * 256 + d)) << 10) + t0 + tq * 4] = v;
    }
}

// ---------------- K2: main recurrent kernel, block = batch row b ------------
struct KParams {
    const int *imask; const float *inp_att; const float *style_tok;
    const float *pre_b1, *pre_b2, *att_bg, *att_bc, *attn_bq, *attn_v;
    const float *deci_b, *dec1_bg, *dec1_bc, *dec2_bg, *dec2_bc, *out_b;
    const unsigned short *wgt;      // bf16 weight block
    const unsigned short *keysT;    // [128][256][1024] bf16
    const unsigned short *encb;     // [128][1024][256] bf16
    float *wacc; float *out;
};

__global__ __launch_bounds__(1024, 1) void k_main(KParams p)
{
    __shared__ float h_att[256], h1[256], h2[256], ctxl[256], wctxl[256];
    __shared__ float stylel[256], astylel[256];
    __shared__ float q_l[256], v_l[256];
    __shared__ float p1_l[256], p_l[128], c_l[256], dec_in[256], o1_l[256], o2_l[256];
    __shared__ float g_l[512], xa[640], xd[512], dense_l[400], last_o[80];
    __shared__ float e_l[1024];
    __shared__ __align__(16) float scratch[8192];   // GEMV/attention partials
    __shared__ float red[32];

    const int tid = threadIdx.x;
    const int b   = blockIdx.x;
    const int mlen = p.imask[b];          // 1..1024

    const unsigned short* W = p.wgt;

    if (tid < 256){
        h_att[tid] = 0.f; h1[tid] = 0.f; h2[tid] = 0.f; ctxl[tid] = 0.f;
        float s = 0.f;
        #pragma unroll
        for (int k = 0; k < 10; k++) s += p.inp_att[b * 10 + k] * p.style_tok[k * 256 + tid];
        stylel[tid] = s; astylel[tid] = fabsf(s);
        v_l[tid] = p.attn_v[tid];
    }
    if (tid < 80) last_o[tid] = 0.f;
    __syncthreads();

    for (int s = 0; s < TDEC; s++){
        // ---- prenet ----
        gemv_bf<3,  80, 256, 256, 16>(W + OFF_PRE_W1, p.pre_b1, last_o, p1_l, scratch, tid);
        gemv_bf<3, 256, 128, 128, 64>(W + OFF_PRE_W2, p.pre_b2, p1_l,  p_l,  scratch, tid);

        // ---- attention GRU: x = [ctx, p], h = h_att ----
        if (tid < 640) xa[tid] = (tid < 256) ? ctxl[tid]
                               : (tid < 384) ? p_l[tid - 256]
                               : h_att[tid - 384];
        __syncthreads();
        gemv_bf<1, 640, 512, 512, 16>(W + OFF_ATT_WG, p.att_bg, xa, g_l, scratch, tid);
        if (tid < 256) xa[384 + tid] = g_l[tid] * h_att[tid];            // r*h
        __syncthreads();
        gemv_bf<2, 640, 256, 256, 32>(W + OFF_ATT_WC, p.att_bc, xa, c_l, scratch, tid);
        if (tid < 256){
            float u = g_l[256 + tid];
            h_att[tid] = u * h_att[tid] + (1.f - u) * c_l[tid];
        }
        __syncthreads();
        gemv_bf<0, 256, 256, 256, 32>(W + OFF_ATTN_WQ, p.attn_bq, h_att, q_l, scratch, tid);

        // ---- attention energies: e[t] = sum_d tanh(keysT[d][t]+q[d])*v[d]
        // thread (tc = tid&127 -> t in [8tc,8tc+8), part = tid>>7 -> 32 d's)
        // 16B coalesced keysT loads, 32 independent loads in flight.
        {
            const int tc   = tid & 127;
            const int part = tid >> 7;
            float acc0=0.f,acc1=0.f,acc2=0.f,acc3=0.f,acc4=0.f,acc5=0.f,acc6=0.f,acc7=0.f;
            if (tc * 8 < mlen){
                const unsigned short* kp = p.keysT + (((size_t)b) << 18)
                                         + ((size_t)(part * 32) << 10) + tc * 8;
                #pragma unroll 8
                for (int dd = 0; dd < 32; dd++){
                    uint4 kv = *(const uint4*)(kp + ((size_t)dd << 10));
                    int d = part * 32 + dd;
                    float qd = q_l[d], vd = v_l[d];
                    acc0 = fmaf(ftanh(__uint_as_float(kv.x << 16)         + qd), vd, acc0);
                    acc1 = fmaf(ftanh(__uint_as_float(kv.x & 0xffff0000u) + qd), vd, acc1);
                    acc2 = fmaf(ftanh(__uint_as_float(kv.y << 16)         + qd), vd, acc2);
                    acc3 = fmaf(ftanh(__uint_as_float(kv.y & 0xffff0000u) + qd), vd, acc3);
                    acc4 = fmaf(ftanh(__uint_as_float(kv.z << 16)         + qd), vd, acc4);
                    acc5 = fmaf(ftanh(__uint_as_float(kv.z & 0xffff0000u) + qd), vd, acc5);
                    acc6 = fmaf(ftanh(__uint_as_float(kv.w << 16)         + qd), vd, acc6);
                    acc7 = fmaf(ftanh(__uint_as_float(kv.w & 0xffff0000u) + qd), vd, acc7);
                }
            }
            float4* s4 = (float4*)(scratch + part * 1024 + tc * 8);
            s4[0] = float4{acc0, acc1, acc2, acc3};
            s4[1] = float4{acc4, acc5, acc6, acc7};
        }
        __syncthreads();
        float ev = -1e30f;
        if (tid < mlen){
            float s8 = 0.f;
            #pragma unroll
            for (int pp = 0; pp < 8; pp++) s8 += scratch[pp * 1024 + tid];
            ev = s8;
        }
        float m  = block_reduce_max(ev, red, tid);
        float a  = (tid < mlen) ? __expf(ev - m) : 0.f;
        float sm = block_reduce_sum(a, red, tid);
        float alpha = a * __builtin_amdgcn_rcpf(sm);   // masked lanes: a=0 -> alpha=0
        e_l[tid] = alpha;
        __builtin_nontemporal_store(alpha,
            &p.out[ALPHA_OFF + (size_t)s * 131072 + ((size_t)b << 10) + tid]);
        __syncthreads();

        // ---- context: ctx[d] = sum_t alpha[t]*enc[t][d]
        // thread (dc = tid&31 -> d in [8dc,8dc+8), tp = tid>>5 -> t = tp+32k)
        {
            const int dc = tid & 31;
            const int tp = tid >> 5;
            float acc0=0.f,acc1=0.f,acc2=0.f,acc3=0.f,acc4=0.f,acc5=0.f,acc6=0.f,acc7=0.f;
            const unsigned short* er = p.encb + (((size_t)b) << 18) + dc * 8;
            for (int t = tp; t < mlen; t += 32){
                uint4 ev4 = *(const uint4*)(er + ((size_t)t << 8));
                float al = e_l[t];
                acc0 = fmaf(al, __uint_as_float(ev4.x << 16),         acc0);
                acc1 = fmaf(al, __uint_as_float(ev4.x & 0xffff0000u), acc1);
                acc2 = fmaf(al, __uint_as_float(ev4.y << 16),         acc2);
                acc3 = fmaf(al, __uint_as_float(ev4.y & 0xffff0000u), acc3);
                acc4 = fmaf(al, __uint_as_float(ev4.z << 16),         acc4);
                acc5 = fmaf(al, __uint_as_float(ev4.z & 0xffff0000u), acc5);
                acc6 = fmaf(al, __uint_as_float(ev4.w << 16),         acc6);
                acc7 = fmaf(al, __uint_as_float(ev4.w & 0xffff0000u), acc7);
            }
            float4* s4 = (float4*)(scratch + tp * 256 + dc * 8);
            s4[0] = float4{acc0, acc1, acc2, acc3};
            s4[1] = float4{acc4, acc5, acc6, acc7};
        }
        __syncthreads();
        float wpv = 0.f;
        if (tid < 256){
            float cs = 0.f;
            #pragma unroll
            for (int pp = 0; pp < 32; pp++) cs += scratch[pp * 256 + tid];
            ctxl[tid]  = cs;
            wctxl[tid] = cs + stylel[tid];
            wpv = astylel[tid] * __builtin_amdgcn_rcpf(fabsf(cs) + astylel[tid]);
        }
        float wsum = block_reduce_sum(wpv, red, tid);
        if (tid == 0) atomicAdd(&p.wacc[s], wsum);

        // ---- dec_in = [h_att, wctx] @ deci_W + b ----
        if (tid < 512) xd[tid] = (tid < 256) ? h_att[tid] : wctxl[tid - 256];
        __syncthreads();
        gemv_bf<0, 512, 256, 256, 32>(W + OFF_DECI_W, p.deci_b, xd, dec_in, scratch, tid);

        // ---- GRU 1 ----
        if (tid < 512) xd[tid] = (tid < 256) ? dec_in[tid] : h1[tid - 256];
        __syncthreads();
        gemv_bf<1, 512, 512, 512, 16>(W + OFF_DEC1_WG, p.dec1_bg, xd, g_l, scratch, tid);
        if (tid < 256) xd[256 + tid] = g_l[tid] * h1[tid];
        __syncthreads();
        gemv_bf<2, 512, 256, 256, 32>(W + OFF_DEC1_WC, p.dec1_bc, xd, c_l, scratch, tid);
        if (tid < 256){
            float u = g_l[256 + tid];
            float hn = u * h1[tid] + (1.f - u) * c_l[tid];
            h1[tid] = hn; o1_l[tid] = hn + dec_in[tid];
        }
        __syncthreads();

        // ---- GRU 2 ----
        if (tid < 512) xd[tid] = (tid < 256) ? o1_l[tid] : h2[tid - 256];
        __syncthreads();
        gemv_bf<1, 512, 512, 512, 16>(W + OFF_DEC2_WG, p.dec2_bg, xd, g_l, scratch, tid);
        if (tid < 256) xd[256 + tid] = g_l[tid] * h2[tid];
        __syncthreads();
        gemv_bf<2, 512, 256, 256, 32>(W + OFF_DEC2_WC, p.dec2_bc, xd, c_l, scratch, tid);
        if (tid < 256){
            float u = g_l[256 + tid];
            float hn = u * h2[tid] + (1.f - u) * c_l[tid];
            h2[tid] = hn; o2_l[tid] = hn + o1_l[tid];
        }
        __syncthreads();

        // ---- output dense (256 -> 400 via padded 512) ----
        gemv_bf<0, 256, 512, 400, 16>(W + OFF_OUT_WP, p.out_b, o2_l, dense_l, scratch, tid);
        if (tid < 400){
            float val = dense_l[tid];
            __builtin_nontemporal_store(val,
                &p.out[(size_t)b * 100000 + (size_t)s * 400 + tid]);
            if (tid >= 320) last_o[tid - 320] = val;
        }
        __syncthreads();
    }
}

// ---------------- K3: finalize weight_pers ----------------------------------
__global__ void k_final(const float* __restrict__ wacc, float* __restrict__ out)
{
    int i = threadIdx.x;
    if (i < TDEC) out[WP_OFF + i] = wacc[i] * (1.0f / 32768.0f);
}

// ---------------------------------------------------------------------------
extern "C" void kernel_launch(void* const* d_in, const int* in_sizes, int n_in,
                              void* d_out, int out_size, void* d_ws, size_t ws_size,
                              hipStream_t stream)
{
    const float* enc        = (const float*)d_in[0];
    const int*   imask      = (const int*)  d_in[1];
    const float* inp_att    = (const float*)d_in[2];
    const float* style_tok  = (const float*)d_in[3];
    const float* pre_W1     = (const float*)d_in[4];
    const float* pre_b1     = (const float*)d_in[5];
    const float* pre_W2     = (const float*)d_in[6];
    const float* pre_b2     = (const float*)d_in[7];
    const float* att_Wg     = (const float*)d_in[8];
    const float* att_bg     = (const float*)d_in[9];
    const float* att_Wc     = (const float*)d_in[10];
    const float* att_bc     = (const float*)d_in[11];
    const float* attn_Wk    = (const float*)d_in[12];
    const float* attn_bk    = (const float*)d_in[13];
    const float* attn_Wq    = (const float*)d_in[14];
    const float* attn_bq    = (const float*)d_in[15];
    const float* attn_v     = (const float*)d_in[16];
    const float* deci_W     = (const float*)d_in[17];
    const float* deci_b     = (const float*)d_in[18];
    const float* dec1_Wg    = (const float*)d_in[19];
    const float* dec1_bg    = (const float*)d_in[20];
    const float* dec1_Wc    = (const float*)d_in[21];
    const float* dec1_bc    = (const float*)d_in[22];
    const float* dec2_Wg    = (const float*)d_in[23];
    const float* dec2_bg    = (const float*)d_in[24];
    const float* dec2_Wc    = (const float*)d_in[25];
    const float* dec2_bc    = (const float*)d_in[26];
    const float* out_W      = (const float*)d_in[27];
    const float* out_b      = (const float*)d_in[28];

    float*          wacc  = (float*)((char*)d_ws + WS_WACC_B);
    unsigned short* wgt   = (unsigned short*)((char*)d_ws + WS_WGT_B);
    unsigned short* keysT = (unsigned short*)((char*)d_ws + WS_KEYS_B);
    unsigned short* encb  = (unsigned short*)((char*)d_ws + WS_ENC_B);
    float* out = (float*)d_out;

    hipMemsetAsync(d_ws, 0, 1024, stream);

    // ---- weight conversions (bf16) ----
    auto cvt = [&](const float* src, size_t off, int n){
        k_cvt_flat<<<(n + 255) / 256, 256, 0, stream>>>(src, wgt + off, n);
    };
    cvt(pre_W1,  OFF_PRE_W1,   80 * 256);
    cvt(pre_W2,  OFF_PRE_W2,  256 * 128);
    cvt(att_Wg,  OFF_ATT_WG,  640 * 512);
    cvt(att_Wc,  OFF_ATT_WC,  640 * 256);
    cvt(attn_Wq, OFF_ATTN_WQ, 256 * 256);
    cvt(deci_W,  OFF_DECI_W,  512 * 256);
    cvt(dec1_Wg, OFF_DEC1_WG, 512 * 512);
    cvt(dec1_Wc, OFF_DEC1_WC, 512 * 256);
    cvt(dec2_Wg, OFF_DEC2_WG, 512 * 512);
    cvt(dec2_Wc, OFF_DEC2_WC, 512 * 256);
    k_cvt_pad<<<(256 * 512) / 256, 256, 0, stream>>>(out_W, wgt + OFF_OUT_WP);

    // ---- enc -> bf16 ----
    k_cvt_flat<<<(33554432 + 255) / 256, 256, 0, stream>>>(enc, encb, 33554432);

    // ---- keys (transposed bf16) ----
    k_keys<<<2048, 256, 0, stream>>>(enc, attn_Wk, attn_bk, keysT);

    KParams kp{imask, inp_att, style_tok,
               pre_b1, pre_b2, att_bg, att_bc, attn_bq, attn_v,
               deci_b, dec1_bg, dec1_bc, dec2_bg, dec2_bc, out_b,
               wgt, keysT, encb, wacc, out};
    k_main<<<BATCH, 1024, 0, stream>>>(kp);

    k_final<<<1, 256, 0, stream>>>(wacc, out);
}